// Round 1
// baseline (7471.223 us; speedup 1.0000x reference)
//
#include <hip/hip_runtime.h>
#include <cstdint>

#define DEVFN __device__ __forceinline__

constexpr float RAD  = 0.1125f;          // 1.5*6*0.025/2
constexpr float R2C  = RAD * RAD;
constexpr float EPSF = 1e-12f;
constexpr float FOPI = 1.27323954473516268615f; // 4/pi

DEVFN float sgnf(float a){ return (a > 0.f) ? 1.f : ((a < 0.f) ? -1.f : 0.f); }

// Geometry for one neighbor offset (ddx,ddy,ddz) = pj - pq (original units).
// Produces 8 (bin, weight) pairs; weight includes poly6 window * factor.
DEVFN void nbr_geom(float ddx, float ddy, float ddz, float factor, int* bins, float* w8)
{
  float x = ddx / RAD, y = ddy / RAD, z = ddz / RAD;
  float sq = x*x + y*y + z*z;
  float omr = 1.f - sq;
  float win = (omr > 0.f) ? omr*omr*omr : 0.f;   // clip((1-r2)^3, 0, 1)
  win *= factor;
  // ball -> cylinder
  float nrm   = sqrtf(sq);
  float xy_sq = x*x + y*y;
  bool  polar = (1.25f*z*z) > xy_sq;
  float s = polar ? sqrtf(3.f*nrm/(nrm + fabsf(z) + EPSF))
                  : (nrm / sqrtf(xy_sq + EPSF));
  float xc = x*s, yc = y*s;
  float zc = polar ? (sgnf(z)*nrm) : (1.5f*z);
  if (sq < EPSF){ xc = 0.f; yc = 0.f; zc = 0.f; }
  // cylinder -> cube (inverse Shirley-Chiu)
  float rxy  = sqrtf(xc*xc + yc*yc);
  bool  xbig = fabsf(xc) >= fabsf(yc);
  float sx = (fabsf(xc) > EPSF) ? xc : 1.f;
  float sy = (fabsf(yc) > EPSF) ? yc : 1.f;
  float u1 = sgnf(xc)*rxy;
  float v1 = u1 * FOPI * atanf(yc / sx);
  float v2 = sgnf(yc)*rxy;
  float u2 = v2 * FOPI * atanf(xc / sy);
  float u = xbig ? u1 : u2;
  float v = xbig ? v1 : v2;
  if (rxy < EPSF){ u = 0.f; v = 0.f; }
  // grid coords (align_corners=True, ks=4)
  float gx = (u *0.5f + 0.5f)*3.f;
  float gy = (v *0.5f + 0.5f)*3.f;
  float gz = (zc*0.5f + 0.5f)*3.f;
  float fx = fminf(fmaxf(floorf(gx), 0.f), 2.f);
  float fy = fminf(fmaxf(floorf(gy), 0.f), 2.f);
  float fz = fminf(fmaxf(floorf(gz), 0.f), 2.f);
  int ix = (int)fx, iy = (int)fy, iz = (int)fz;
  float tx = gx - fx, ty = gy - fy, tz = gz - fz;
  float wx[2] = {1.f - tx, tx};
  float wy[2] = {1.f - ty, ty};
  float wz[2] = {1.f - tz, tz};
  #pragma unroll
  for (int dz2 = 0; dz2 < 2; ++dz2)
    #pragma unroll
    for (int dy2 = 0; dy2 < 2; ++dy2)
      #pragma unroll
      for (int dx2 = 0; dx2 < 2; ++dx2){
        int c = (dz2 << 2) | (dy2 << 1) | dx2;
        bins[c] = ((iz + dz2)*4 + (iy + dy2))*4 + (ix + dx2);
        w8[c]   = wx[dx2]*wy[dy2]*wz[dz2]*win;
      }
}

// ---------------------------------------------------------------------------
// k_conv0: conv0_fluid + conv0_obstacle + dense0 + concat + relu -> inp1[N][96]
// one 256-thread block per query particle
// ---------------------------------------------------------------------------
__global__ __launch_bounds__(256)
void k_conv0(const float* __restrict__ pos, const float* __restrict__ vel,
             const float* __restrict__ box, const float* __restrict__ boxf,
             const float* __restrict__ Wf, const float* __restrict__ bcf,
             const float* __restrict__ Wo, const float* __restrict__ bco,
             const float* __restrict__ Wd0, const float* __restrict__ bd0,
             const int* __restrict__ nfi, const int* __restrict__ nbi,
             int KF, int KB, float* __restrict__ inp1)
{
  const int n = blockIdx.x;
  const int t = threadIdx.x;
  __shared__ float Af[64*4];
  __shared__ float Ao[64*3];
  __shared__ float gwf[64][8]; __shared__ int gbf[64][8]; __shared__ int gif[64];
  __shared__ float gwo[32][8]; __shared__ int gbo[32][8]; __shared__ int gio[32];
  __shared__ float red[256];

  const float qx = pos[3*n], qy = pos[3*n+1], qz = pos[3*n+2];

  if (t < 256) { if (t < 256) Af[t] = 0.f; }
  if (t < 192) Ao[t] = 0.f;

  if (t < 64) {                         // wave 0: fluid neighbors (KF=64)
    const int k = t;
    const int j = nfi[(size_t)n*KF + k];
    const float px = pos[3*j], py = pos[3*j+1], pz = pos[3*j+2];
    const float ddx = px - qx, ddy = py - qy, ddz = pz - qz;
    const float d2 = ddx*ddx + ddy*ddy + ddz*ddz;
    unsigned long long zm = __ballot(j == 0);
    int fz = __ffsll(zm) - 1;
    float factor = (j != 0) ? 1.f
                 : ((k == fz && d2 <= R2C && n != 0) ? 1.f : 0.f);
    int bins[8]; float w8[8];
    nbr_geom(ddx, ddy, ddz, factor, bins, w8);
    gif[k] = j;
    #pragma unroll
    for (int q = 0; q < 8; ++q){ gwf[k][q] = w8[q]; gbf[k][q] = bins[q]; }
  } else if (t < 128) {                 // wave 1: obstacle neighbors (KB=32)
    const int k = t & 63;
    const bool act = k < KB;
    const int j = act ? nbi[(size_t)n*KB + k] : 1;
    float ddx = 0.f, ddy = 0.f, ddz = 0.f, d2 = 1e30f;
    if (act){
      const float px = box[3*j], py = box[3*j+1], pz = box[3*j+2];
      ddx = px - qx; ddy = py - qy; ddz = pz - qz;
      d2 = ddx*ddx + ddy*ddy + ddz*ddz;
    }
    unsigned long long zm = __ballot(act && j == 0);
    int fz = __ffsll(zm) - 1;
    float factor = (j != 0) ? 1.f : ((k == fz && d2 <= R2C) ? 1.f : 0.f);
    if (act){
      int bins[8]; float w8[8];
      nbr_geom(ddx, ddy, ddz, factor, bins, w8);
      gio[k] = j;
      #pragma unroll
      for (int q = 0; q < 8; ++q){ gwo[k][q] = w8[q]; gbo[k][q] = bins[q]; }
    }
  }
  __syncthreads();

  // scatter fluid: 64 nbrs x 4 ch over 256 threads
  {
    const int k = t >> 2, c = t & 3;
    const int j = gif[k];
    const float fj = (c == 0) ? 1.f : vel[3*j + (c-1)];
    #pragma unroll
    for (int q = 0; q < 8; ++q)
      unsafeAtomicAdd(&Af[gbf[k][q]*4 + c], gwf[k][q]*fj);
  }
  // scatter obstacle: 32 nbrs x 3 ch over threads < 128
  if (t < 128){
    const int k = t >> 2, c = t & 3;
    if (c < 3){
      const int j = gio[k];
      const float fj = boxf[3*j + c];
      #pragma unroll
      for (int q = 0; q < 8; ++q)
        unsafeAtomicAdd(&Ao[gbo[k][q]*3 + c], gwo[k][q]*fj);
    }
  }
  __syncthreads();

  // contraction: a_cf (K=256), a_co (K=192), dense0, bias, relu, concat
  const int o = t & 31, g = t >> 5;
  float p1 = 0.f;
  for (int b = g*8; b < g*8 + 8; ++b)
    #pragma unroll
    for (int c = 0; c < 4; ++c)
      p1 += Af[b*4 + c] * Wf[(b*4 + c)*32 + o];
  red[t] = p1;
  __syncthreads();
  float a_cf = 0.f;
  if (t < 32){ for (int g2 = 0; g2 < 8; ++g2) a_cf += red[t + 32*g2]; }
  __syncthreads();
  float p2 = 0.f;
  for (int b = g*8; b < g*8 + 8; ++b)
    #pragma unroll
    for (int c = 0; c < 3; ++c)
      p2 += Ao[b*3 + c] * Wo[(b*3 + c)*32 + o];
  red[t] = p2;
  __syncthreads();
  if (t < 32){
    float a_co = 0.f;
    for (int g2 = 0; g2 < 8; ++g2) a_co += red[t + 32*g2];
    const float vx = vel[3*n], vy = vel[3*n+1], vz = vel[3*n+2];
    const float a_df = Wd0[0*32 + t] + Wd0[1*32 + t]*vx + Wd0[2*32 + t]*vy + Wd0[3*32 + t]*vz;
    const size_t base = (size_t)n * 96;
    inp1[base +      t] = fmaxf(a_co + bco[t], 0.f);
    inp1[base + 32 + t] = fmaxf(a_cf + bcf[t], 0.f);
    inp1[base + 64 + t] = fmaxf(a_df + bd0[t], 0.f);
  }
}

// ---------------------------------------------------------------------------
// k_scatter<C>: build A_ext[n][Kp] = [ A(64 bins x C) | feat(n) (C cols) ]
// one 256-thread block per query; fluid neighbor list (KF=64)
// ---------------------------------------------------------------------------
template<int C>
__global__ __launch_bounds__(256)
void k_scatter(const float* __restrict__ pos, const float* __restrict__ feat,
               const int* __restrict__ nfi, int n0, int Kp,
               float* __restrict__ Aout)
{
  const int n = n0 + blockIdx.x;
  const int t = threadIdx.x;
  __shared__ __align__(16) float A[64*C];
  __shared__ float gw[64][8];
  __shared__ int   gb[64][8];
  __shared__ int   gidx[64];

  const float qx = pos[3*n], qy = pos[3*n+1], qz = pos[3*n+2];

  for (int i = t; i < 64*C; i += 256) A[i] = 0.f;

  if (t < 64){
    const int k = t;
    const int j = nfi[(size_t)n*64 + k];
    const float px = pos[3*j], py = pos[3*j+1], pz = pos[3*j+2];
    const float ddx = px - qx, ddy = py - qy, ddz = pz - qz;
    const float d2 = ddx*ddx + ddy*ddy + ddz*ddz;
    unsigned long long zm = __ballot(j == 0);
    int fz = __ffsll(zm) - 1;
    float factor = (j != 0) ? 1.f
                 : ((k == fz && d2 <= R2C && n != 0) ? 1.f : 0.f);
    int bins[8]; float w8[8];
    nbr_geom(ddx, ddy, ddz, factor, bins, w8);
    gidx[k] = j;
    #pragma unroll
    for (int q = 0; q < 8; ++q){ gw[k][q] = w8[q]; gb[k][q] = bins[q]; }
  }
  __syncthreads();

  if (C == 96){
    const int c = t & 127, kk0 = t >> 7;      // 2 nbrs in flight
    if (c < 96){
      for (int it = 0; it < 32; ++it){
        const int k = it*2 + kk0;
        const float fj = feat[(size_t)gidx[k]*C + c];
        #pragma unroll
        for (int q = 0; q < 8; ++q)
          unsafeAtomicAdd(&A[gb[k][q]*C + c], gw[k][q]*fj);
      }
    }
  } else {                                     // C == 64
    const int c = t & 63, kk0 = t >> 6;        // 4 nbrs in flight
    for (int it = 0; it < 16; ++it){
      const int k = it*4 + kk0;
      const float fj = feat[(size_t)gidx[k]*C + c];
      #pragma unroll
      for (int q = 0; q < 8; ++q)
        unsafeAtomicAdd(&A[gb[k][q]*C + c], gw[k][q]*fj);
    }
  }
  __syncthreads();

  const size_t base = (size_t)(n - n0) * Kp;
  float4* dst = (float4*)(Aout + base);
  const float4* srcA = (const float4*)A;
  for (int i = t; i < (64*C)/4; i += 256) dst[i] = srcA[i];
  for (int i = t; i < C; i += 256) Aout[base + 64*C + i] = feat[(size_t)n*C + i];
}

// ---------------------------------------------------------------------------
// k_gemm: accum[n][o] += sum_k A[n][k] * Fext[k][o]   (f32, K-split via atomics)
// Fext rows: [0,kSplitPt) -> conv filter F, [kSplitPt,Kp) -> dense W
// BM=128, BN=64, BK=32; 8x4 acc per thread; grid = (tiles, 8 segments)
// ---------------------------------------------------------------------------
__global__ __launch_bounds__(256)
void k_gemm(const float* __restrict__ A, const float* __restrict__ F,
            const float* __restrict__ Wd, float* __restrict__ accum,
            int n0, int n1, int Kp, int kSplitPt, int segBlocks)
{
  const int t = threadIdx.x;
  const int CHa = n1 - n0;
  const int kbTot = Kp >> 5;
  int kb0 = (int)blockIdx.y * segBlocks;
  int kb1 = kb0 + segBlocks; if (kb1 > kbTot) kb1 = kbTot;
  if (kb0 >= kb1) return;

  __shared__ __align__(16) float At[32][132];   // transposed A tile [kk][row]
  __shared__ __align__(16) float Bt[32][68];    // [kk][o]

  const int tc = t & 15, tr = t >> 4;
  const int rowBase = (int)blockIdx.x * 128;

  float acc[8][4];
  #pragma unroll
  for (int i = 0; i < 8; ++i)
    #pragma unroll
    for (int j = 0; j < 4; ++j) acc[i][j] = 0.f;

  for (int kb = kb0; kb < kb1; ++kb){
    const int k0 = kb << 5;
    // stage A (transpose into LDS)
    {
      const int row = t & 127;
      const int kvb = (t >> 7) * 4;
      const int cRow = rowBase + row;
      const float* ap = A + (size_t)cRow * Kp + k0;
      #pragma unroll
      for (int i = 0; i < 4; ++i){
        const int kv = kvb + i;
        float4 v = make_float4(0.f, 0.f, 0.f, 0.f);
        if (cRow < CHa) v = *(const float4*)(ap + kv*4);
        At[kv*4+0][row] = v.x; At[kv*4+1][row] = v.y;
        At[kv*4+2][row] = v.z; At[kv*4+3][row] = v.w;
      }
    }
    // stage B
    #pragma unroll
    for (int i = 0; i < 2; ++i){
      const int idx  = t*2 + i;
      const int brow = idx >> 4;
      const int ov   = (idx & 15) * 4;
      const int krow = k0 + brow;
      const float* src = (krow < kSplitPt)
                       ? (F  + (size_t)krow * 64 + ov)
                       : (Wd + (size_t)(krow - kSplitPt) * 64 + ov);
      *(float4*)&Bt[brow][ov] = *(const float4*)src;
    }
    __syncthreads();
    #pragma unroll 8
    for (int kk = 0; kk < 32; ++kk){
      const float4 a0 = *(const float4*)&At[kk][8*tr];
      const float4 a1 = *(const float4*)&At[kk][8*tr + 4];
      const float4 b  = *(const float4*)&Bt[kk][4*tc];
      const float av[8] = {a0.x, a0.y, a0.z, a0.w, a1.x, a1.y, a1.z, a1.w};
      const float bv[4] = {b.x, b.y, b.z, b.w};
      #pragma unroll
      for (int i = 0; i < 8; ++i)
        #pragma unroll
        for (int j = 0; j < 4; ++j)
          acc[i][j] = fmaf(av[i], bv[j], acc[i][j]);
    }
    __syncthreads();
  }

  #pragma unroll
  for (int i = 0; i < 8; ++i){
    const int cRow = rowBase + 8*tr + i;
    if (cRow < CHa){
      float* op = accum + (size_t)(n0 + cRow)*64 + 4*tc;
      #pragma unroll
      for (int j = 0; j < 4; ++j) unsafeAtomicAdd(op + j, acc[i][j]);
    }
  }
}

// ---------------------------------------------------------------------------
// k_epi: v = accum + bc + bd (+ resid); outRaw = v; outRelu = max(v,0)
// ---------------------------------------------------------------------------
__global__ __launch_bounds__(256)
void k_epi(const float* __restrict__ accum, const float* __restrict__ bc,
           const float* __restrict__ bd, const float* __restrict__ resid,
           float* __restrict__ outRaw, float* __restrict__ outRelu, int total)
{
  const int i = blockIdx.x*256 + threadIdx.x;
  if (i >= total) return;
  const int o = i & 63;
  float v = accum[i] + bc[o] + bd[o];
  if (resid)  v += resid[i];
  if (outRaw)  outRaw[i]  = v;
  if (outRelu) outRelu[i] = fmaxf(v, 0.f);
}

// ---------------------------------------------------------------------------
extern "C" void kernel_launch(void* const* d_in, const int* in_sizes, int n_in,
                              void* d_out, int out_size, void* d_ws, size_t ws_size,
                              hipStream_t stream)
{
  const float* pos  = (const float*)d_in[0];
  const float* vel  = (const float*)d_in[1];
  const float* box  = (const float*)d_in[2];
  const float* boxf = (const float*)d_in[3];
  const float* Wc0f = (const float*)d_in[4];
  const float* bc0f = (const float*)d_in[5];
  const float* Wc0o = (const float*)d_in[6];
  const float* bc0o = (const float*)d_in[7];
  const float* Wd0  = (const float*)d_in[8];
  const float* bd0  = (const float*)d_in[9];
  const float* Wc1  = (const float*)d_in[10];
  const float* bc1  = (const float*)d_in[11];
  const float* Wd1  = (const float*)d_in[12];
  const float* bd1  = (const float*)d_in[13];
  const float* Wc2  = (const float*)d_in[14];
  const float* bc2  = (const float*)d_in[15];
  const float* Wd2  = (const float*)d_in[16];
  const float* bd2  = (const float*)d_in[17];
  const int* nfi = (const int*)d_in[18];
  const int* nbi = (const int*)d_in[20];
  const int NF = in_sizes[0]/3;
  const int NB = in_sizes[2]/3;
  const int KF = in_sizes[18]/NF;
  const int KB = in_sizes[20]/NF;
  (void)NB;
  float* out = (float*)d_out;

  float* ws   = (float*)d_ws;
  float* inp1 = ws;                               // NF*96
  float* ans1 = inp1 + (size_t)NF*96;             // NF*64
  float* inp2 = ans1 + (size_t)NF*64;             // NF*64
  float* accum= inp2 + (size_t)NF*64;             // NF*64
  float* Abuf = accum + (size_t)NF*64;

  const int Kp1 = 96*64 + 96;   // 6240 (multiple of 32)
  const int Kp2 = 64*64 + 64;   // 4160 (multiple of 32)

  const size_t head = (size_t)(Abuf - ws);
  const size_t totF = ws_size / sizeof(float);
  long long availF = (totF > head) ? (long long)(totF - head) : 0;
  long long chF = availF / Kp1;
  int CH = (int)((chF < 128) ? 128 : ((chF > NF) ? NF : chF));
  if (CH < NF) CH &= ~127;               // multiple of 128 when chunking
  if (CH < 128) CH = 128;

  const int segBlocks1 = ((Kp1 >> 5) + 7) / 8;   // 25
  const int segBlocks2 = ((Kp2 >> 5) + 7) / 8;   // 17

  // layer 0
  k_conv0<<<NF, 256, 0, stream>>>(pos, vel, box, boxf, Wc0f, bc0f, Wc0o, bc0o,
                                  Wd0, bd0, nfi, nbi, KF, KB, inp1);

  // layer 1: conv1 + dense1 (dense folded into GEMM K-extension)
  hipMemsetAsync(accum, 0, (size_t)NF*64*sizeof(float), stream);
  for (int n0 = 0; n0 < NF; n0 += CH){
    const int n1  = (n0 + CH < NF) ? (n0 + CH) : NF;
    const int CHa = n1 - n0;
    k_scatter<96><<<CHa, 256, 0, stream>>>(pos, inp1, nfi, n0, Kp1, Abuf);
    const int tiles = (CHa + 127) / 128;
    k_gemm<<<dim3(tiles, 8), 256, 0, stream>>>(Abuf, Wc1, Wd1, accum,
                                               n0, n1, Kp1, 96*64, segBlocks1);
  }
  k_epi<<<(NF*64 + 255)/256, 256, 0, stream>>>(accum, bc1, bd1, nullptr,
                                               ans1, inp2, NF*64);

  // layer 2: conv2 + dense2 + residual
  hipMemsetAsync(accum, 0, (size_t)NF*64*sizeof(float), stream);
  for (int n0 = 0; n0 < NF; n0 += CH){
    const int n1  = (n0 + CH < NF) ? (n0 + CH) : NF;
    const int CHa = n1 - n0;
    k_scatter<64><<<CHa, 256, 0, stream>>>(pos, inp2, nfi, n0, Kp2, Abuf);
    const int tiles = (CHa + 127) / 128;
    k_gemm<<<dim3(tiles, 8), 256, 0, stream>>>(Abuf, Wc2, Wd2, accum,
                                               n0, n1, Kp2, 64*64, segBlocks2);
  }
  k_epi<<<(NF*64 + 255)/256, 256, 0, stream>>>(accum, bc2, bd2, ans1,
                                               out, nullptr, NF*64);
}

// Round 3
// 265.557 us; speedup vs baseline: 28.1342x; 28.1342x over previous
//
#include <hip/hip_runtime.h>
#include <cstdint>

#define DEVFN __device__ __forceinline__

using hh8 = __attribute__((ext_vector_type(8))) _Float16; // 8 fp16 (4 VGPR)
using f4  = __attribute__((ext_vector_type(4))) float;    // MFMA acc

constexpr float RAD  = 0.1125f;          // 1.5*6*0.025/2
constexpr float R2C  = RAD * RAD;
constexpr float EPSF = 1e-12f;
constexpr float FOPI = 1.27323954473516268615f; // 4/pi

DEVFN float sgnf(float a){ return (a > 0.f) ? 1.f : ((a < 0.f) ? -1.f : 0.f); }

DEVFN unsigned short f2h(float f){             // f32 -> fp16 (RNE via v_cvt)
  _Float16 h = (_Float16)f;
  union { _Float16 h; unsigned short u; } x; x.h = h; return x.u;
}
DEVFN hh8 ld_hh8(const unsigned short* p){ return *(const hh8*)p; }

// Geometry for one neighbor offset (pj - pq). 8 (bin, weight) pairs; weight
// includes poly6 window * factor.  (verified correct in round 1)
DEVFN void nbr_geom(float ddx, float ddy, float ddz, float factor, int* bins, float* w8)
{
  float x = ddx / RAD, y = ddy / RAD, z = ddz / RAD;
  float sq = x*x + y*y + z*z;
  float omr = 1.f - sq;
  float win = (omr > 0.f) ? omr*omr*omr : 0.f;
  win *= factor;
  float nrm   = sqrtf(sq);
  float xy_sq = x*x + y*y;
  bool  polar = (1.25f*z*z) > xy_sq;
  float s = polar ? sqrtf(3.f*nrm/(nrm + fabsf(z) + EPSF))
                  : (nrm / sqrtf(xy_sq + EPSF));
  float xc = x*s, yc = y*s;
  float zc = polar ? (sgnf(z)*nrm) : (1.5f*z);
  if (sq < EPSF){ xc = 0.f; yc = 0.f; zc = 0.f; }
  float rxy  = sqrtf(xc*xc + yc*yc);
  bool  xbig = fabsf(xc) >= fabsf(yc);
  float sx = (fabsf(xc) > EPSF) ? xc : 1.f;
  float sy = (fabsf(yc) > EPSF) ? yc : 1.f;
  float u1 = sgnf(xc)*rxy;
  float v1 = u1 * FOPI * atanf(yc / sx);
  float v2 = sgnf(yc)*rxy;
  float u2 = v2 * FOPI * atanf(xc / sy);
  float u = xbig ? u1 : u2;
  float v = xbig ? v1 : v2;
  if (rxy < EPSF){ u = 0.f; v = 0.f; }
  float gx = (u *0.5f + 0.5f)*3.f;
  float gy = (v *0.5f + 0.5f)*3.f;
  float gz = (zc*0.5f + 0.5f)*3.f;
  float fx = fminf(fmaxf(floorf(gx), 0.f), 2.f);
  float fy = fminf(fmaxf(floorf(gy), 0.f), 2.f);
  float fz = fminf(fmaxf(floorf(gz), 0.f), 2.f);
  int ix = (int)fx, iy = (int)fy, iz = (int)fz;
  float tx = gx - fx, ty = gy - fy, tz = gz - fz;
  float wx[2] = {1.f - tx, tx};
  float wy[2] = {1.f - ty, ty};
  float wz[2] = {1.f - tz, tz};
  #pragma unroll
  for (int dz2 = 0; dz2 < 2; ++dz2)
    #pragma unroll
    for (int dy2 = 0; dy2 < 2; ++dy2)
      #pragma unroll
      for (int dx2 = 0; dx2 < 2; ++dx2){
        int c = (dz2 << 2) | (dy2 << 1) | dx2;
        bins[c] = ((iz + dz2)*4 + (iy + dy2))*4 + (ix + dx2);
        w8[c]   = wx[dx2]*wy[dy2]*wz[dz2]*win;
      }
}

// ---------------------------------------------------------------------------
// k_conv0: conv0_fluid + conv0_obstacle + dense0 + concat + relu -> inp1[N][96]
// scatter-as-GEMM: per query, W[64x64] (plain LDS writes, lane owns column),
// then A = W @ Fj via MFMA.  One 256-thread WG per query.
// ---------------------------------------------------------------------------
__global__ __launch_bounds__(256)
void k_conv0(const float* __restrict__ pos, const float* __restrict__ vel,
             const float* __restrict__ box, const float* __restrict__ boxf,
             const float* __restrict__ Wfilt, const float* __restrict__ bcf,
             const float* __restrict__ Ofilt, const float* __restrict__ bco,
             const float* __restrict__ Wd0, const float* __restrict__ bd0,
             const int* __restrict__ nfi, const int* __restrict__ nbi,
             int KB, float* __restrict__ inp1)
{
  const int n = blockIdx.x, t = threadIdx.x;
  const int lane = t & 63, w = t >> 6, r = lane & 15, h = lane >> 4;

  __shared__ __align__(16) unsigned short LWf[64*64];  // [b][k ^ ((b&7)<<3)]
  __shared__ __align__(16) unsigned short LWo[64*32];  // [b][k ^ ((b&3)<<3)]
  __shared__ __align__(16) unsigned short LBf[16*64];  // [c][k ^ ((c&7)<<3)], rows>=4 zero
  __shared__ __align__(16) unsigned short LBo[16*32];  // [c][k ^ ((c&3)<<3)], rows>=3 zero
  __shared__ float Af[64*4];
  __shared__ float Ao[64*3];
  __shared__ int gjf[64]; __shared__ int gjo[32];
  __shared__ float red[256];

  const float qx = pos[3*n], qy = pos[3*n+1], qz = pos[3*n+2];
  int bins[8]; float w8[8];

  if (w == 0){                              // fluid geometry (KF=64)
    const int k = lane;
    const int j = nfi[(size_t)n*64 + k];
    const float ddx = pos[3*j] - qx, ddy = pos[3*j+1] - qy, ddz = pos[3*j+2] - qz;
    const float d2 = ddx*ddx + ddy*ddy + ddz*ddz;
    unsigned long long zm = __ballot(j == 0);
    int fz = __ffsll(zm) - 1;
    float factor = (j != 0) ? 1.f : ((k == fz && d2 <= R2C && n != 0) ? 1.f : 0.f);
    nbr_geom(ddx, ddy, ddz, factor, bins, w8);
    gjf[k] = j;
  } else if (w == 1){                       // obstacle geometry (KB=32)
    const int k = lane;
    const bool act = k < KB;
    const int j = act ? nbi[(size_t)n*KB + k] : 1;
    float ddx = 0.f, ddy = 0.f, ddz = 0.f, d2 = 1e30f;
    if (act){
      ddx = box[3*j] - qx; ddy = box[3*j+1] - qy; ddz = box[3*j+2] - qz;
      d2 = ddx*ddx + ddy*ddy + ddz*ddz;
    }
    unsigned long long zm = __ballot(act && j == 0);
    int fz = __ffsll(zm) - 1;
    float factor = (j != 0) ? 1.f : ((k == fz && d2 <= R2C) ? 1.f : 0.f);
    nbr_geom(ddx, ddy, ddz, factor, bins, w8);
    if (act) gjo[k] = j;
  } else {                                  // zero the fp16 LDS tiles
    int4 z4 = make_int4(0,0,0,0);
    for (int i = t-128; i < 512; i += 128) *(int4*)&LWf[i*8] = z4;
    for (int i = t-128; i < 256; i += 128) *(int4*)&LWo[i*8] = z4;
    if (t-128 < 128) *(int4*)&LBf[(t-128)*8] = z4;
    if (t-128 <  64) *(int4*)&LBo[(t-128)*8] = z4;
  }
  __syncthreads();

  if (w == 0){
    #pragma unroll
    for (int q = 0; q < 8; ++q){
      int b = bins[q];
      LWf[b*64 + (lane ^ ((b&7)<<3))] = f2h(w8[q]);
    }
  } else if (w == 1){
    if (lane < KB){
      #pragma unroll
      for (int q = 0; q < 8; ++q){
        int b = bins[q];
        LWo[b*32 + (lane ^ ((b&3)<<3))] = f2h(w8[q]);
      }
    }
  } else if (w == 2){                       // BT fluid features [1, vel]
    const int k = lane; const int j = gjf[k];
    LBf[0*64 + k] = f2h(1.f);
    LBf[1*64 + (k ^ 8)]  = f2h(vel[3*j]);
    LBf[2*64 + (k ^ 16)] = f2h(vel[3*j+1]);
    LBf[3*64 + (k ^ 24)] = f2h(vel[3*j+2]);
  } else {                                  // BT obstacle features (normals)
    if (lane < KB){
      const int k = lane; const int j = gjo[k];
      LBo[0*32 + k]        = f2h(boxf[3*j]);
      LBo[1*32 + (k ^ 8)]  = f2h(boxf[3*j+1]);
      LBo[2*32 + (k ^ 16)] = f2h(boxf[3*j+2]);
    }
  }
  __syncthreads();

  // MFMA: A = W @ Fj.  Wave w owns bins [16w,16w+16).
  f4 aF = {0.f,0.f,0.f,0.f}, aO = {0.f,0.f,0.f,0.f};
  {
    const int b = 16*w + r;
    #pragma unroll
    for (int ks = 0; ks < 2; ++ks){
      hh8 a  = ld_hh8(&LWf[b*64 + (((ks*4+h) ^ (b&7))<<3)]);
      hh8 bb = ld_hh8(&LBf[r*64 + (((ks*4+h) ^ (r&7))<<3)]);
      aF = __builtin_amdgcn_mfma_f32_16x16x32_f16(a, bb, aF, 0,0,0);
    }
    hh8 a2 = ld_hh8(&LWo[b*32 + ((h ^ (b&3))<<3)]);
    hh8 b2 = ld_hh8(&LBo[r*32 + ((h ^ (r&3))<<3)]);
    aO = __builtin_amdgcn_mfma_f32_16x16x32_f16(a2, b2, aO, 0,0,0);
  }
  // D layout: col = lane&15, row = (lane>>4)*4 + reg  [HW-verified]
  #pragma unroll
  for (int rr = 0; rr < 4; ++rr){
    int b2 = 16*w + h*4 + rr;
    if (r < 4) Af[b2*4 + r] = aF[rr];
    if (r < 3) Ao[b2*3 + r] = aO[rr];
  }
  __syncthreads();

  // contraction + dense0 + concat + relu  (round-1 verified code)
  const int o = t & 31, g = t >> 5;
  float p1 = 0.f;
  for (int b2 = g*8; b2 < g*8 + 8; ++b2)
    #pragma unroll
    for (int c = 0; c < 4; ++c)
      p1 += Af[b2*4 + c] * Wfilt[(b2*4 + c)*32 + o];
  red[t] = p1;
  __syncthreads();
  float a_cf = 0.f;
  if (t < 32){ for (int g2 = 0; g2 < 8; ++g2) a_cf += red[t + 32*g2]; }
  __syncthreads();
  float p2 = 0.f;
  for (int b2 = g*8; b2 < g*8 + 8; ++b2)
    #pragma unroll
    for (int c = 0; c < 3; ++c)
      p2 += Ao[b2*3 + c] * Ofilt[(b2*3 + c)*32 + o];
  red[t] = p2;
  __syncthreads();
  if (t < 32){
    float a_co = 0.f;
    for (int g2 = 0; g2 < 8; ++g2) a_co += red[t + 32*g2];
    const float vx = vel[3*n], vy = vel[3*n+1], vz = vel[3*n+2];
    const float a_df = Wd0[t] + Wd0[32 + t]*vx + Wd0[64 + t]*vy + Wd0[96 + t]*vz;
    const size_t base = (size_t)n * 96;
    inp1[base +      t] = fmaxf(a_co + bco[t], 0.f);
    inp1[base + 32 + t] = fmaxf(a_cf + bcf[t], 0.f);
    inp1[base + 64 + t] = fmaxf(a_df + bd0[t], 0.f);
  }
}

// ---------------------------------------------------------------------------
// k1_scatter<C>: per query, A[64 bins][C] = W @ Fj via MFMA; append dense-ext
// feat row + zero pad; write fp16 row to Abuf with chunk-XOR swizzle (key =
// local row & 7) so k2's linear LDS staging yields conflict-free frag reads.
// ---------------------------------------------------------------------------
template<int C>
__global__ __launch_bounds__(256)
void k1_scatter(const float* __restrict__ pos, const float* __restrict__ feat,
                const int* __restrict__ nfi, int n0, unsigned short* __restrict__ Abuf)
{
  constexpr int Kpad = 64*C + C + (C == 96 ? 32 : 0);   // 6272 / 4160
  constexpr int CT = C/16;
  const int nloc = blockIdx.x;
  const int n = n0 + nloc;
  const int t = threadIdx.x;
  const int lane = t & 63, w = t >> 6, r = lane & 15, h = lane >> 4;

  __shared__ __align__(16) unsigned short sh[4096 + C*64]; // W | BT ; reused as Aout
  unsigned short* W  = sh;
  unsigned short* BT = sh + 4096;
  __shared__ int gj[64];

  int bins[8]; float w8[8];
  if (w == 0){
    const float qx = pos[3*n], qy = pos[3*n+1], qz = pos[3*n+2];
    const int k = lane;
    const int j = nfi[(size_t)n*64 + k];
    const float ddx = pos[3*j] - qx, ddy = pos[3*j+1] - qy, ddz = pos[3*j+2] - qz;
    const float d2 = ddx*ddx + ddy*ddy + ddz*ddz;
    unsigned long long zm = __ballot(j == 0);
    int fz = __ffsll(zm) - 1;
    float factor = (j != 0) ? 1.f : ((k == fz && d2 <= R2C && n != 0) ? 1.f : 0.f);
    nbr_geom(ddx, ddy, ddz, factor, bins, w8);
    gj[k] = j;
  } else {
    int4 z4 = make_int4(0,0,0,0);
    for (int i = t - 64; i < 512; i += 192) *(int4*)&W[i*8] = z4;
  }
  __syncthreads();

  if (w == 0){
    #pragma unroll
    for (int q = 0; q < 8; ++q){
      int b = bins[q];
      W[b*64 + (lane ^ ((b&7)<<3))] = f2h(w8[q]);
    }
  }
  // BT gather: BT[c][k] = feat[j_k][c]  (coalesced reads over c)
  for (int i = t; i < C*64; i += 256){
    int k = i / C, c = i - k*C;
    int j = gj[k];
    BT[c*64 + (k ^ ((c&7)<<3))] = f2h(feat[(size_t)j*C + c]);
  }
  __syncthreads();

  // MFMA: wave w owns bins [16w, 16w+16)
  f4 acc[CT];
  #pragma unroll
  for (int ct = 0; ct < CT; ++ct) acc[ct] = f4{0.f,0.f,0.f,0.f};
  const int b = 16*w + r;
  #pragma unroll
  for (int ks = 0; ks < 2; ++ks){
    hh8 a = ld_hh8(&W[b*64 + (((ks*4+h) ^ (b&7))<<3)]);
    #pragma unroll
    for (int ct = 0; ct < CT; ++ct){
      int c = ct*16 + r;
      hh8 bb = ld_hh8(&BT[c*64 + (((ks*4+h) ^ (c&7))<<3)]);
      acc[ct] = __builtin_amdgcn_mfma_f32_16x16x32_f16(a, bb, acc[ct], 0,0,0);
    }
  }
  __syncthreads();                         // all frag reads done; reuse sh

  unsigned short* Aout = sh;               // Kpad fp16 row
  #pragma unroll
  for (int ct = 0; ct < CT; ++ct){
    int c = ct*16 + r;
    #pragma unroll
    for (int rr = 0; rr < 4; ++rr){
      int b2 = 16*w + h*4 + rr;            // D: col=lane&15, row=(lane>>4)*4+reg
      Aout[b2*C + c] = f2h(acc[ct][rr]);
    }
  }
  if (t < C) Aout[64*C + t] = f2h(feat[(size_t)n*C + t]);   // dense extension
  if constexpr (C == 96){
    if (t >= 96 && t < 128) Aout[6240 + t - 96] = 0;         // zero pad
  }
  __syncthreads();

  const int key = nloc & 7;
  const size_t rowBase = (size_t)nloc * Kpad;
  for (int ch = t; ch < Kpad/8; ch += 256){
    int4 v = *(const int4*)&Aout[ch*8];
    *(int4*)&Abuf[rowBase + (size_t)(ch ^ key)*8] = v;
  }
}

// ---------------------------------------------------------------------------
// k_bpack: BpkT[o][kp] fp16 (o-major, chunk-swizzled by o&7) from f32 F + Wd.
// ---------------------------------------------------------------------------
__global__ __launch_bounds__(256)
void k_bpack(const float* __restrict__ F, const float* __restrict__ Wd,
             int kSplit, int Cd, int Kpad, unsigned short* __restrict__ BpkT)
{
  int idx = blockIdx.x*256 + threadIdx.x;
  int chunks = Kpad/8;
  if (idx >= 64*chunks) return;
  int o = idx / chunks, ch = idx - o*chunks;
  union { int4 v; unsigned short u[8]; } pk;
  #pragma unroll
  for (int e = 0; e < 8; ++e){
    int kp = ch*8 + e;
    float f = 0.f;
    if (kp < kSplit)            f = F[(size_t)kp*64 + o];
    else if (kp < kSplit + Cd)  f = Wd[(size_t)(kp - kSplit)*64 + o];
    pk.u[e] = f2h(f);
  }
  *(int4*)&BpkT[((size_t)o*chunks + (ch ^ (o&7)))*8] = pk.v;
}

// ---------------------------------------------------------------------------
// k2_gemm: partial[seg][n][o] = A[n][k] @ B[k][o] over seg's K-range.
// BM=128, BN=64, BK=64, fp16 MFMA 16x16x32; reg-staged LDS; swizzled layouts.
// ---------------------------------------------------------------------------
__global__ __launch_bounds__(256)
void k2_gemm(const unsigned short* __restrict__ Abuf, const unsigned short* __restrict__ BpkT,
             float* __restrict__ partial, int n0, int CHa, int Kpad, int ktot,
             int sB, int NF)
{
  const int t = threadIdx.x;
  const int lane = t & 63, w = t >> 6, r = lane & 15, h = lane >> 4;
  const int seg = blockIdx.y;
  const int ks0 = seg*sB;
  const int ks1 = (ks0 + sB < ktot) ? (ks0 + sB) : ktot;
  const int rowBase = blockIdx.x * 128;

  __shared__ __align__(16) unsigned short Asub[128*64];
  __shared__ __align__(16) unsigned short Bsub[64*64];

  f4 acc[2][4];
  #pragma unroll
  for (int i = 0; i < 2; ++i)
    #pragma unroll
    for (int j = 0; j < 4; ++j) acc[i][j] = f4{0.f,0.f,0.f,0.f};

  for (int ks = ks0; ks < ks1; ++ks){
    #pragma unroll
    for (int i = 0; i < 4; ++i){           // stage A tile (16KB)
      int lin = i*256 + t;
      int row = lin >> 3, lc = lin & 7;
      int grow = rowBase + row; if (grow >= CHa) grow = CHa - 1;
      int4 v = *(const int4*)&Abuf[(size_t)grow*Kpad + ks*64 + lc*8];
      *(int4*)&Asub[lin*8] = v;
    }
    #pragma unroll
    for (int i = 0; i < 2; ++i){           // stage B tile (8KB)
      int lin = i*256 + t;
      int o = lin >> 3, lc = lin & 7;
      int4 v = *(const int4*)&BpkT[(size_t)o*Kpad + ks*64 + lc*8];
      *(int4*)&Bsub[lin*8] = v;
    }
    __syncthreads();
    #pragma unroll
    for (int kh = 0; kh < 2; ++kh){
      hh8 a0 = ld_hh8(&Asub[(w*32 +      r)*64 + (((kh*4+h) ^ (r&7))<<3)]);
      hh8 a1 = ld_hh8(&Asub[(w*32 + 16 + r)*64 + (((kh*4+h) ^ (r&7))<<3)]);
      #pragma unroll
      for (int nt = 0; nt < 4; ++nt){
        hh8 bb = ld_hh8(&Bsub[(nt*16 + r)*64 + (((kh*4+h) ^ (r&7))<<3)]);
        acc[0][nt] = __builtin_amdgcn_mfma_f32_16x16x32_f16(a0, bb, acc[0][nt], 0,0,0);
        acc[1][nt] = __builtin_amdgcn_mfma_f32_16x16x32_f16(a1, bb, acc[1][nt], 0,0,0);
      }
    }
    __syncthreads();
  }

  #pragma unroll
  for (int mt = 0; mt < 2; ++mt)
    #pragma unroll
    for (int rr = 0; rr < 4; ++rr){
      int m = rowBase + w*32 + mt*16 + h*4 + rr;
      if (m < CHa){
        float* op = partial + ((size_t)seg*NF + n0 + m)*64;
        #pragma unroll
        for (int nt = 0; nt < 4; ++nt)
          op[nt*16 + r] = acc[mt][nt][rr];
      }
    }
}

// ---------------------------------------------------------------------------
// k_epi: v = sum_s partial[s] + bc + bd (+resid); outRaw = v; outRelu = relu(v)
// ---------------------------------------------------------------------------
__global__ __launch_bounds__(256)
void k_epi(const float* __restrict__ partial, const float* __restrict__ bc,
           const float* __restrict__ bd, const float* __restrict__ resid,
           float* __restrict__ outRaw, float* __restrict__ outRelu, int total)
{
  const int i = blockIdx.x*256 + threadIdx.x;
  if (i >= total) return;
  float v = 0.f;
  #pragma unroll
  for (int s = 0; s < 8; ++s) v += partial[(size_t)s*total + i];
  const int o = i & 63;
  v += bc[o] + bd[o];
  if (resid)   v += resid[i];
  if (outRaw)  outRaw[i]  = v;
  if (outRelu) outRelu[i] = fmaxf(v, 0.f);
}

// ---------------------------------------------------------------------------
extern "C" void kernel_launch(void* const* d_in, const int* in_sizes, int n_in,
                              void* d_out, int out_size, void* d_ws, size_t ws_size,
                              hipStream_t stream)
{
  const float* pos  = (const float*)d_in[0];
  const float* vel  = (const float*)d_in[1];
  const float* box  = (const float*)d_in[2];
  const float* boxf = (const float*)d_in[3];
  const float* Wc0f = (const float*)d_in[4];
  const float* bc0f = (const float*)d_in[5];
  const float* Wc0o = (const float*)d_in[6];
  const float* bc0o = (const float*)d_in[7];
  const float* Wd0  = (const float*)d_in[8];
  const float* bd0  = (const float*)d_in[9];
  const float* Wc1  = (const float*)d_in[10];
  const float* bc1  = (const float*)d_in[11];
  const float* Wd1  = (const float*)d_in[12];
  const float* bd1  = (const float*)d_in[13];
  const float* Wc2  = (const float*)d_in[14];
  const float* bc2  = (const float*)d_in[15];
  const float* Wd2  = (const float*)d_in[16];
  const float* bd2  = (const float*)d_in[17];
  const int* nfi = (const int*)d_in[18];
  const int* nbi = (const int*)d_in[20];
  const int NF = in_sizes[0]/3;
  const int KB = in_sizes[20]/NF;
  float* out = (float*)d_out;

  char* wsb = (char*)d_ws;
  auto alloc = [&](size_t bytes){ char* p = wsb; wsb += (bytes + 255) & ~(size_t)255; return p; };
  float* inp1    = (float*)alloc((size_t)NF*96*4);
  float* ans1    = (float*)alloc((size_t)NF*64*4);
  float* inp2    = (float*)alloc((size_t)NF*64*4);
  float* partial = (float*)alloc((size_t)8*NF*64*4);
  unsigned short* Bpk1 = (unsigned short*)alloc((size_t)64*6272*2);
  unsigned short* Bpk2 = (unsigned short*)alloc((size_t)64*4160*2);
  unsigned short* Abuf = (unsigned short*)wsb;
  size_t usedB = (size_t)(wsb - (char*)d_ws);
  size_t availUS = (ws_size > usedB) ? (ws_size - usedB)/2 : 0;

  auto chunkOf = [&](int Kpad)->int{
    long long c = (long long)(availUS / (size_t)Kpad);
    if (c >= NF) return NF;
    int ch = (int)c & ~127;
    if (ch < 128) ch = 128;
    return ch;
  };

  // layer 0
  k_conv0<<<NF, 256, 0, stream>>>(pos, vel, box, boxf, Wc0f, bc0f, Wc0o, bc0o,
                                  Wd0, bd0, nfi, nbi, KB, inp1);
  // prepack B (conv filter + dense W, transposed + swizzled, fp16)
  k_bpack<<<(64*784 + 255)/256, 256, 0, stream>>>(Wc1, Wd1, 6144, 96, 6272, Bpk1);
  k_bpack<<<(64*520 + 255)/256, 256, 0, stream>>>(Wc2, Wd2, 4096, 64, 4160, Bpk2);

  // layer 1: conv1 + dense1 (K-extension)
  {
    int CH = chunkOf(6272);
    for (int n0 = 0; n0 < NF; n0 += CH){
      int CHa = (n0 + CH < NF) ? CH : (NF - n0);
      k1_scatter<96><<<CHa, 256, 0, stream>>>(pos, inp1, nfi, n0, Abuf);
      int tiles = (CHa + 127)/128;
      k2_gemm<<<dim3(tiles, 8), 256, 0, stream>>>(Abuf, Bpk1, partial, n0, CHa,
                                                  6272, 98, 13, NF);
    }
    k_epi<<<(NF*64 + 255)/256, 256, 0, stream>>>(partial, bc1, bd1, nullptr,
                                                 ans1, inp2, NF*64);
  }
  // layer 2: conv2 + dense2 + residual
  {
    int CH = chunkOf(4160);
    for (int n0 = 0; n0 < NF; n0 += CH){
      int CHa = (n0 + CH < NF) ? CH : (NF - n0);
      k1_scatter<64><<<CHa, 256, 0, stream>>>(pos, inp2, nfi, n0, Abuf);
      int tiles = (CHa + 127)/128;
      k2_gemm<<<dim3(tiles, 8), 256, 0, stream>>>(Abuf, Bpk2, partial, n0, CHa,
                                                  4160, 65, 9, NF);
    }
    k_epi<<<(NF*64 + 255)/256, 256, 0, stream>>>(partial, bc2, bd2, ans1,
                                                 out, nullptr, NF*64);
  }
}